// Round 4
// baseline (509.484 us; speedup 1.0000x reference)
//
#include <hip/hip_runtime.h>
#include <stdint.h>

// Problem: out[b,f,o] = sum_i x[b,f,i]*W[f,i,o] + bias[f,o]
// B=4096, F=64, DIN=256, DOUT=256, fp32 in/out, bf16 MFMA compute.
#define BATCH 4096
#define FEAT  64
#define DIN   256
#define DOUT  256

typedef __attribute__((ext_vector_type(8))) short  short8;   // bf16x8 MFMA operand (4 VGPRs)
typedef __attribute__((ext_vector_type(4))) float  float4v;  // MFMA acc
typedef __attribute__((ext_vector_type(4))) unsigned int uint4v;

// Pack two fp32 -> dword of two bf16 (round-half-up: +0x8000 then take hi16).
__device__ __forceinline__ unsigned int pack_bf16(float lo, float hi) {
    unsigned int ulo = __builtin_bit_cast(unsigned int, lo) + 0x8000u;
    unsigned int uhi = __builtin_bit_cast(unsigned int, hi) + 0x8000u;
    return __builtin_amdgcn_perm(uhi, ulo, 0x07060302u);
}

// 8 consecutive fp32 -> short8 of bf16 (element j = bf16(v[j])).
__device__ __forceinline__ short8 pack8(float4v lo, float4v hi) {
    uint4v p;
    p.x = pack_bf16(lo.x, lo.y);
    p.y = pack_bf16(lo.z, lo.w);
    p.z = pack_bf16(hi.x, hi.y);
    p.w = pack_bf16(hi.z, hi.w);
    return __builtin_bit_cast(short8, p);
}

// ---- W prep: fp32 W[f][k][n] -> bf16 fragment-major Wb[f][k/8][n][k%8] ----
// One-time per launch (~8 us): 16 MB read, 8 MB write. Each lane's B-fragment
// in the main kernel is then a single 16-B dwordx4 load, bit-identical values.
__global__ __launch_bounds__(256)
void wprep_kernel(const float* __restrict__ w, unsigned short* __restrict__ wb) {
    const int blk = blockIdx.x;          // = f*32 + kb8   (kb8 = k >> 3)
    const int n   = threadIdx.x;         // 0..255
    const float* src = w + (size_t)blk * 8 * DOUT + n;   // W[f][kb8*8][n]
    float v0 = src[0 * DOUT], v1 = src[1 * DOUT];
    float v2 = src[2 * DOUT], v3 = src[3 * DOUT];
    float v4 = src[4 * DOUT], v5 = src[5 * DOUT];
    float v6 = src[6 * DOUT], v7 = src[7 * DOUT];
    uint4v p;
    p.x = pack_bf16(v0, v1);
    p.y = pack_bf16(v2, v3);
    p.z = pack_bf16(v4, v5);
    p.w = pack_bf16(v6, v7);
    *(uint4v*)(wb + ((size_t)blk * DOUT + n) * 8) = p;   // 16 B, fully coalesced
}

// ---- Fast path: NO LDS, NO barrier. 4 waves split 2x2 (m x n):
// wave (wm,wn) owns rows [b0+wm*32, +32) x cols [wn*128, +128).
// A rows are wave-private -> x fp32 loaded straight to regs (per l16 the
// 4 q-lanes read 128 B contiguous), packed to bf16 in-reg, double-buffered
// across K-steps. B from L2-resident Wb, one dwordx4 per fragment.
__global__ __launch_bounds__(256, 3)
void nlinear_kernel(const float* __restrict__ x,
                    const short8* __restrict__ wb,   // bf16 fragment-major
                    const float* __restrict__ bias,
                    float* __restrict__ out) {
    const int tid  = threadIdx.x;
    const int f    = blockIdx.x & 63;   // same f -> same XCD (64%8==0): Wb[f] L2-hot
    const int mb   = blockIdx.x >> 6;
    const int b0   = mb * 64;

    const int lane = tid & 63;
    const int wv   = tid >> 6;      // 0..3
    const int wm   = wv >> 1;       // row-half: 32 rows
    const int wn   = wv & 1;        // col-half: 128 cols
    const int q    = lane >> 4;     // quad 0..3
    const int l16  = lane & 15;
    const int n0   = wn * 128;
    const int m0   = b0 + wm * 32;  // this wave's global row base

    // ---- Accumulators initialized with bias (col-dependent only) ----
    float4v acc[2][8];   // [mi 16-row subtile][s 16-col subtile]
    #pragma unroll
    for (int s = 0; s < 8; ++s) {
        float bv = bias[f * DOUT + n0 + s * 16 + l16];
        acc[0][s] = (float4v){bv, bv, bv, bv};
        acc[1][s] = (float4v){bv, bv, bv, bv};
    }

    // A source: lane (q,l16) reads x[m0 + mi*16 + l16][f][kb + q*8 .. +7]
    const float* xr0 = x + ((size_t)(m0 + l16) * FEAT + f) * DIN + q * 8;
    const float* xr1 = xr0 + (size_t)16 * FEAT * DIN;
    // B source: Wb[f][kb8][n][j], kb8 = it*4 + q, n = n0 + s*16 + l16
    const short8* wbase = wb + (size_t)f * 32 * DOUT + n0 + l16;

    // Prologue: x for it=0 into buffer A.
    float4v xA0 = *(const float4v*)(xr0);
    float4v xA1 = *(const float4v*)(xr0 + 4);
    float4v xA2 = *(const float4v*)(xr1);
    float4v xA3 = *(const float4v*)(xr1 + 4);

    #pragma unroll
    for (int t = 0; t < 4; ++t) {
        const int itA = 2 * t, itB = 2 * t + 1;

        // Prefetch it=2t+1 x into buffer B (HBM latency hides under MFMAs).
        float4v xB0 = *(const float4v*)(xr0 + itB * 32);
        float4v xB1 = *(const float4v*)(xr0 + itB * 32 + 4);
        float4v xB2 = *(const float4v*)(xr1 + itB * 32);
        float4v xB3 = *(const float4v*)(xr1 + itB * 32 + 4);

        {   // ---- K-step itA: consume buffer A ----
            short8 af0 = pack8(xA0, xA1);
            short8 af1 = pack8(xA2, xA3);
            const short8* wk = wbase + (size_t)(itA * 4 + q) * DOUT;
            short8 bf[8];
            #pragma unroll
            for (int s = 0; s < 8; ++s) bf[s] = wk[s * 16];
            #pragma unroll
            for (int s = 0; s < 8; ++s) {
                acc[0][s] = __builtin_amdgcn_mfma_f32_16x16x32_bf16(
                    af0, bf[s], acc[0][s], 0, 0, 0);
                acc[1][s] = __builtin_amdgcn_mfma_f32_16x16x32_bf16(
                    af1, bf[s], acc[1][s], 0, 0, 0);
            }
        }

        // Prefetch it=2t+2 x into buffer A.
        if (t < 3) {
            xA0 = *(const float4v*)(xr0 + (itB + 1) * 32);
            xA1 = *(const float4v*)(xr0 + (itB + 1) * 32 + 4);
            xA2 = *(const float4v*)(xr1 + (itB + 1) * 32);
            xA3 = *(const float4v*)(xr1 + (itB + 1) * 32 + 4);
        }

        {   // ---- K-step itB: consume buffer B ----
            short8 af0 = pack8(xB0, xB1);
            short8 af1 = pack8(xB2, xB3);
            const short8* wk = wbase + (size_t)(itB * 4 + q) * DOUT;
            short8 bf[8];
            #pragma unroll
            for (int s = 0; s < 8; ++s) bf[s] = wk[s * 16];
            #pragma unroll
            for (int s = 0; s < 8; ++s) {
                acc[0][s] = __builtin_amdgcn_mfma_f32_16x16x32_bf16(
                    af0, bf[s], acc[0][s], 0, 0, 0);
                acc[1][s] = __builtin_amdgcn_mfma_f32_16x16x32_bf16(
                    af1, bf[s], acc[1][s], 0, 0, 0);
            }
        }
    }

    // ---- Epilogue: C/D layout col = l16 (+s*16), row = q*4 + r (+mi*16) ----
    float* ob = out + ((size_t)m0 * FEAT + f) * DOUT + n0;
    #pragma unroll
    for (int mi = 0; mi < 2; ++mi) {
        #pragma unroll
        for (int r = 0; r < 4; ++r) {
            float* orow = ob + (size_t)(mi * 16 + q * 4 + r) * (FEAT * DOUT);
            #pragma unroll
            for (int s = 0; s < 8; ++s)
                orow[s * 16 + l16] = acc[mi][s][r];
        }
    }
}

// ---- Fallback (no workspace): proven 481us baseline, fp32 W in-loop ----
#define A_STRIDE 264
__global__ __launch_bounds__(256, 2)
void nlinear_fallback(const float* __restrict__ x,
                      const float* __restrict__ w,
                      const float* __restrict__ bias,
                      float* __restrict__ out) {
    __shared__ __align__(16) unsigned short Alds[64 * A_STRIDE];

    const int tid = threadIdx.x;
    const int f   = blockIdx.x & 63;
    const int mb  = blockIdx.x >> 6;
    const int b0  = mb * 64;

    {
        const float* xb = x + (size_t)(b0 * FEAT + f) * DIN;
        #pragma unroll
        for (int i = 0; i < 8; ++i) {
            int chunk = tid + 256 * i;
            int row   = chunk >> 5;
            int c8    = (chunk & 31) * 8;
            const float* g = xb + row * (FEAT * DIN) + c8;
            float4v a0 = *(const float4v*)g;
            float4v a1 = *(const float4v*)(g + 4);
            uint4v p;
            p.x = pack_bf16(a0.x, a0.y);
            p.y = pack_bf16(a0.z, a0.w);
            p.z = pack_bf16(a1.x, a1.y);
            p.w = pack_bf16(a1.z, a1.w);
            *(uint4v*)&Alds[row * A_STRIDE + c8] = p;
        }
    }
    __syncthreads();

    const int lane = tid & 63;
    const int wv   = tid >> 6;
    const int q    = lane >> 4;
    const int l16  = lane & 15;
    const int n0   = wv * 64;

    float4v acc[4][4];
    #pragma unroll
    for (int s = 0; s < 4; ++s) {
        float bv = bias[f * DOUT + n0 + s * 16 + l16];
        #pragma unroll
        for (int mi = 0; mi < 4; ++mi)
            acc[mi][s] = (float4v){bv, bv, bv, bv};
    }

    const float* wp = w + (size_t)f * (DIN * DOUT) + n0 + q * 8 * DOUT + l16;
    const unsigned short* albase = Alds + l16 * A_STRIDE + q * 8;

    #pragma unroll 2
    for (int it = 0; it < 8; ++it) {
        const int kb = it * 32;
        const float* wk = wp + kb * DOUT;

        short8 bfrag[4];
        #pragma unroll
        for (int s = 0; s < 4; ++s) {
            float v0 = wk[0 * DOUT + s * 16];
            float v1 = wk[1 * DOUT + s * 16];
            float v2 = wk[2 * DOUT + s * 16];
            float v3 = wk[3 * DOUT + s * 16];
            float v4 = wk[4 * DOUT + s * 16];
            float v5 = wk[5 * DOUT + s * 16];
            float v6 = wk[6 * DOUT + s * 16];
            float v7 = wk[7 * DOUT + s * 16];
            uint4v p;
            p.x = pack_bf16(v0, v1);
            p.y = pack_bf16(v2, v3);
            p.z = pack_bf16(v4, v5);
            p.w = pack_bf16(v6, v7);
            bfrag[s] = __builtin_bit_cast(short8, p);
        }

        short8 afrag[4];
        #pragma unroll
        for (int mi = 0; mi < 4; ++mi)
            afrag[mi] = *(const short8*)(albase + mi * 16 * A_STRIDE + kb);

        #pragma unroll
        for (int mi = 0; mi < 4; ++mi)
            #pragma unroll
            for (int s = 0; s < 4; ++s)
                acc[mi][s] = __builtin_amdgcn_mfma_f32_16x16x32_bf16(
                    afrag[mi], bfrag[s], acc[mi][s], 0, 0, 0);
    }

    float* ob = out + (size_t)(b0 * FEAT + f) * DOUT + n0;
    #pragma unroll
    for (int mi = 0; mi < 4; ++mi) {
        #pragma unroll
        for (int r = 0; r < 4; ++r) {
            int m = mi * 16 + q * 4 + r;
            float* orow = ob + m * (FEAT * DOUT);
            #pragma unroll
            for (int s = 0; s < 4; ++s)
                orow[s * 16 + l16] = acc[mi][s][r];
        }
    }
}

extern "C" void kernel_launch(void* const* d_in, const int* in_sizes, int n_in,
                              void* d_out, int out_size, void* d_ws, size_t ws_size,
                              hipStream_t stream) {
    const float* x    = (const float*)d_in[0];   // (4096, 64, 256) fp32
    const float* w    = (const float*)d_in[1];   // (64, 256, 256) fp32
    const float* bias = (const float*)d_in[2];   // (64, 256) fp32
    float* out = (float*)d_out;                  // (4096, 64, 256) fp32

    // Workspace need: bf16 fragment-major W, 64*256*256*2 = 8 MiB.
    const size_t WB_BYTES = (size_t)FEAT * DIN * DOUT * sizeof(unsigned short);

    if (d_ws != nullptr && ws_size >= WB_BYTES) {
        unsigned short* wbuf = (unsigned short*)d_ws;
        wprep_kernel<<<dim3(FEAT * (DIN / 8)), dim3(256), 0, stream>>>(w, wbuf);
        nlinear_kernel<<<dim3(FEAT * (BATCH / 64)), dim3(256), 0, stream>>>(
            x, (const short8*)wbuf, bias, out);
    } else {
        // No usable workspace: proven baseline path, no OOB risk.
        nlinear_fallback<<<dim3(FEAT * (BATCH / 64)), dim3(256), 0, stream>>>(
            x, w, bias, out);
    }
}

// Round 6
// 449.479 us; speedup vs baseline: 1.1335x; 1.1335x over previous
//
#include <hip/hip_runtime.h>
#include <stdint.h>

// Problem: out[b,f,o] = sum_i x[b,f,i]*W[f,i,o] + bias[f,o]
// B=4096, F=64, DIN=256, DOUT=256, fp32 in/out, bf16 MFMA compute.
#define BATCH 4096
#define FEAT  64
#define DIN   256
#define DOUT  256

typedef __attribute__((ext_vector_type(8))) short  short8;   // bf16x8 MFMA operand (4 VGPRs)
typedef __attribute__((ext_vector_type(4))) float  float4v;  // MFMA acc
typedef __attribute__((ext_vector_type(4))) unsigned int uint4v;

// Pack two fp32 -> dword of two bf16 (round-half-up: +0x8000 then take hi16).
__device__ __forceinline__ unsigned int pack_bf16(float lo, float hi) {
    unsigned int ulo = __builtin_bit_cast(unsigned int, lo) + 0x8000u;
    unsigned int uhi = __builtin_bit_cast(unsigned int, hi) + 0x8000u;
    return __builtin_amdgcn_perm(uhi, ulo, 0x07060302u);
}

// LDS A-tile: 64 rows x (256 + 8 pad) bf16 = 33792 B. Row stride 264*2=528 B
// (16B aligned; 132 dwords == 4 mod 32 banks -> frag reads bank-uniform).
#define A_STRIDE 264

// ---- W prep: fp32 W[f][k][n] -> bf16 fragment-major Wb[f][k/8][n][k%8] ----
// XCD-ALIGNED grid: blk = kb8*64 + f, so blk%8 == f%8 -- the SAME XCD that
// nlinear's consumer blocks for feature f run on (their bid%8 == f%8 too).
// Wb[f] (128 KiB) is thus written into, and read from, ONE XCD's L2:
// all B-fragment loads in the main loop become local-L2 hits (~200cy),
// never cross-XCD L3 round-trips (~600cy). That cross-XCD scatter was the
// round-3/4 latency bug (wprep used blk = f*32+kb8 -> XCD = kb8%8).
__global__ __launch_bounds__(256)
void wprep_kernel(const float* __restrict__ w, unsigned short* __restrict__ wb) {
    const int blk = blockIdx.x;
    const int f   = blk & 63;            // XCD = blk%8 = f%8
    const int kb8 = blk >> 6;            // 0..31
    const int n   = threadIdx.x;         // 0..255
    const float* src = w + ((size_t)f * DIN + kb8 * 8) * DOUT + n;  // W[f][kb8*8][n]
    float v0 = src[0 * DOUT], v1 = src[1 * DOUT];
    float v2 = src[2 * DOUT], v3 = src[3 * DOUT];
    float v4 = src[4 * DOUT], v5 = src[5 * DOUT];
    float v6 = src[6 * DOUT], v7 = src[7 * DOUT];
    uint4v p;
    p.x = pack_bf16(v0, v1);
    p.y = pack_bf16(v2, v3);
    p.z = pack_bf16(v4, v5);
    p.w = pack_bf16(v6, v7);
    // Wb[f][kb8][n][0..7], 16 B per thread, coalesced
    *(uint4v*)(wb + (((size_t)f * 32 + kb8) * DOUT + n) * 8) = p;
}

// ---- Shared block prologue: stage x-tile to bf16 LDS ----
__device__ __forceinline__ void stage_x_tile(const float* __restrict__ x,
                                             unsigned short* Alds,
                                             int b0, int f, int tid) {
    const float* xb = x + (size_t)(b0 * FEAT + f) * DIN;  // row stride FEAT*DIN
    #pragma unroll
    for (int i = 0; i < 8; ++i) {
        int chunk = tid + 256 * i;          // 2048 chunks of 8 floats
        int row   = chunk >> 5;             // 0..63
        int c8    = (chunk & 31) * 8;       // 0..248
        const float* g = xb + row * (FEAT * DIN) + c8;
        float4v a0 = *(const float4v*)g;
        float4v a1 = *(const float4v*)(g + 4);
        uint4v p;
        p.x = pack_bf16(a0.x, a0.y);
        p.y = pack_bf16(a0.z, a0.w);
        p.z = pack_bf16(a1.x, a1.y);
        p.w = pack_bf16(a1.z, a1.w);
        *(uint4v*)&Alds[row * A_STRIDE + c8] = p;
    }
}

// ---- Fast path: LDS-staged A (proven round-3 structure) + B double-buffer.
// 4 waves n-split (64 cols each); per K-step: 4 B dwordx4 (local-L2 Wb),
// 4 ds_read_b128 A-frags, 16 MFMA. B-frags for it+1 are loaded BEFORE the
// MFMA cluster of it -> one full K-step of latency cover + 16-wave/CU TLP.
__global__ __launch_bounds__(256, 3)
void nlinear_kernel(const float* __restrict__ x,
                    const short8* __restrict__ wb,   // bf16 fragment-major
                    const float* __restrict__ bias,
                    float* __restrict__ out) {
    __shared__ __align__(16) unsigned short Alds[64 * A_STRIDE];

    const int tid = threadIdx.x;
    const int f   = blockIdx.x & 63;   // 64 m-blocks of same f -> same XCD (64%8==0)
    const int mb  = blockIdx.x >> 6;
    const int b0  = mb * 64;

    stage_x_tile(x, Alds, b0, f, tid);

    const int lane = tid & 63;
    const int wv   = tid >> 6;      // wave 0..3 -> n-slice of 64 cols
    const int q    = lane >> 4;     // quad 0..3
    const int l16  = lane & 15;
    const int n0   = wv * 64;

    // B frag source: Wb[f][kb8][n][j]; lane (q,l16) wants kb8 = it*4 + q,
    // n = n0 + s*16 + l16, j=0..7 contiguous -> one short8 (dwordx4) per frag.
    const short8* wbase = wb + (size_t)f * 32 * DOUT + n0 + l16;

    // Issue it=0 B loads BEFORE the barrier (covers them with the stage tail).
    short8 bf[4];
    {
        const short8* wk = wbase + (size_t)q * DOUT;
        #pragma unroll
        for (int s = 0; s < 4; ++s) bf[s] = wk[s * 16];
    }

    // ---- Accumulators initialized with bias (col-dependent only) ----
    float4v acc[4][4];   // [m-subtile][n-subtile]
    #pragma unroll
    for (int s = 0; s < 4; ++s) {
        float bv = bias[f * DOUT + n0 + s * 16 + l16];
        #pragma unroll
        for (int mi = 0; mi < 4; ++mi)
            acc[mi][s] = (float4v){bv, bv, bv, bv};
    }

    __syncthreads();   // the only barrier

    const unsigned short* albase = Alds + l16 * A_STRIDE + q * 8;

    #pragma unroll
    for (int it = 0; it < 8; ++it) {
        const int kb = it * 32;

        // Prefetch it+1 B fragments (one dwordx4 each, XCD-local L2).
        short8 bfn[4];
        const bool have_next = (it < 7);
        if (have_next) {
            const short8* wk = wbase + (size_t)((it + 1) * 4 + q) * DOUT;
            #pragma unroll
            for (int s = 0; s < 4; ++s) bfn[s] = wk[s * 16];
        }

        // A fragments: one ds_read_b128 each (A[m=l16+mi*16][kb+q*8 .. +7])
        short8 afrag[4];
        #pragma unroll
        for (int mi = 0; mi < 4; ++mi)
            afrag[mi] = *(const short8*)(albase + mi * 16 * A_STRIDE + kb);

        #pragma unroll
        for (int mi = 0; mi < 4; ++mi)
            #pragma unroll
            for (int s = 0; s < 4; ++s)
                acc[mi][s] = __builtin_amdgcn_mfma_f32_16x16x32_bf16(
                    afrag[mi], bf[s], acc[mi][s], 0, 0, 0);

        if (have_next) {
            #pragma unroll
            for (int s = 0; s < 4; ++s) bf[s] = bfn[s];
        }
    }

    // ---- Epilogue: C/D layout col = l16 (+s*16), row = q*4 + r (+mi*16) ----
    float* ob = out + (size_t)(b0 * FEAT + f) * DOUT + n0;
    #pragma unroll
    for (int mi = 0; mi < 4; ++mi) {
        #pragma unroll
        for (int r = 0; r < 4; ++r) {
            int m = mi * 16 + q * 4 + r;
            float* orow = ob + m * (FEAT * DOUT);
            #pragma unroll
            for (int s = 0; s < 4; ++s)
                orow[s * 16 + l16] = acc[mi][s][r];
        }
    }
}

// ---- Fallback (no workspace): proven 481us baseline, fp32 W in-loop ----
__global__ __launch_bounds__(256, 2)
void nlinear_fallback(const float* __restrict__ x,
                      const float* __restrict__ w,
                      const float* __restrict__ bias,
                      float* __restrict__ out) {
    __shared__ __align__(16) unsigned short Alds[64 * A_STRIDE];

    const int tid = threadIdx.x;
    const int f   = blockIdx.x & 63;
    const int mb  = blockIdx.x >> 6;
    const int b0  = mb * 64;

    stage_x_tile(x, Alds, b0, f, tid);
    __syncthreads();

    const int lane = tid & 63;
    const int wv   = tid >> 6;
    const int q    = lane >> 4;
    const int l16  = lane & 15;
    const int n0   = wv * 64;

    float4v acc[4][4];
    #pragma unroll
    for (int s = 0; s < 4; ++s) {
        float bv = bias[f * DOUT + n0 + s * 16 + l16];
        #pragma unroll
        for (int mi = 0; mi < 4; ++mi)
            acc[mi][s] = (float4v){bv, bv, bv, bv};
    }

    const float* wp = w + (size_t)f * (DIN * DOUT) + n0 + q * 8 * DOUT + l16;
    const unsigned short* albase = Alds + l16 * A_STRIDE + q * 8;

    #pragma unroll 2
    for (int it = 0; it < 8; ++it) {
        const int kb = it * 32;
        const float* wk = wp + kb * DOUT;

        short8 bfrag[4];
        #pragma unroll
        for (int s = 0; s < 4; ++s) {
            float v0 = wk[0 * DOUT + s * 16];
            float v1 = wk[1 * DOUT + s * 16];
            float v2 = wk[2 * DOUT + s * 16];
            float v3 = wk[3 * DOUT + s * 16];
            float v4 = wk[4 * DOUT + s * 16];
            float v5 = wk[5 * DOUT + s * 16];
            float v6 = wk[6 * DOUT + s * 16];
            float v7 = wk[7 * DOUT + s * 16];
            uint4v p;
            p.x = pack_bf16(v0, v1);
            p.y = pack_bf16(v2, v3);
            p.z = pack_bf16(v4, v5);
            p.w = pack_bf16(v6, v7);
            bfrag[s] = __builtin_bit_cast(short8, p);
        }

        short8 afrag[4];
        #pragma unroll
        for (int mi = 0; mi < 4; ++mi)
            afrag[mi] = *(const short8*)(albase + mi * 16 * A_STRIDE + kb);

        #pragma unroll
        for (int mi = 0; mi < 4; ++mi)
            #pragma unroll
            for (int s = 0; s < 4; ++s)
                acc[mi][s] = __builtin_amdgcn_mfma_f32_16x16x32_bf16(
                    afrag[mi], bfrag[s], acc[mi][s], 0, 0, 0);
    }

    float* ob = out + (size_t)(b0 * FEAT + f) * DOUT + n0;
    #pragma unroll
    for (int mi = 0; mi < 4; ++mi) {
        #pragma unroll
        for (int r = 0; r < 4; ++r) {
            int m = mi * 16 + q * 4 + r;
            float* orow = ob + m * (FEAT * DOUT);
            #pragma unroll
            for (int s = 0; s < 4; ++s)
                orow[s * 16 + l16] = acc[mi][s][r];
        }
    }
}

extern "C" void kernel_launch(void* const* d_in, const int* in_sizes, int n_in,
                              void* d_out, int out_size, void* d_ws, size_t ws_size,
                              hipStream_t stream) {
    const float* x    = (const float*)d_in[0];   // (4096, 64, 256) fp32
    const float* w    = (const float*)d_in[1];   // (64, 256, 256) fp32
    const float* bias = (const float*)d_in[2];   // (64, 256) fp32
    float* out = (float*)d_out;                  // (4096, 64, 256) fp32

    // Workspace need: bf16 fragment-major W, 64*256*256*2 = 8 MiB.
    const size_t WB_BYTES = (size_t)FEAT * DIN * DOUT * sizeof(unsigned short);

    if (d_ws != nullptr && ws_size >= WB_BYTES) {
        unsigned short* wbuf = (unsigned short*)d_ws;
        // Prep: blk = kb8*64 + f -> XCD f%8, matching the consumer blocks.
        wprep_kernel<<<dim3(FEAT * (DIN / 8)), dim3(256), 0, stream>>>(w, wbuf);
        nlinear_kernel<<<dim3(FEAT * (BATCH / 64)), dim3(256), 0, stream>>>(
            x, (const short8*)wbuf, bias, out);
    } else {
        // No usable workspace: proven baseline path, no OOB risk.
        nlinear_fallback<<<dim3(FEAT * (BATCH / 64)), dim3(256), 0, stream>>>(
            x, w, bias, out);
    }
}